// Round 6
// baseline (101.289 us; speedup 1.0000x reference)
//
#include <hip/hip_runtime.h>

#define HH 512
#define WW 512
#define NB 16
#define NTOT (NB * 3 * HH * WW)     // 12582912
#define CHS (HH * WW)               // 262144 (channel stride), CHS % 3 == 1

// Each thread owns a 4-wide x 4-tall strip. No LDS (except final reduction).
// Register history of 2 previous rows (own 4 cols); current row holds 8 cols
// (own 4 + dx-halo +/-2). ycc built on the fly from a 12-float x window:
// ycc[f] = x[f-j]*mat[0][j] + x[f-j+1]*mat[1][j] + x[f-j+2]*mat[2][j] + bias[j],
// j = f % 3 (faithful to reference's reshape(-1,3) @ mat over flat NCHW).
// 12 unique offsets, each counted twice in the reference -> factor 2 in inv.
// Blocks with bx in {1,2} and by < 15 are provably interior: no clamps/selects.

#define SC2 (-0.0072134752044448f)  // -1/(2*sigma^2) * log2(e), sigma=10

__device__ __forceinline__ int mod3s(int v) { return v >= 3 ? v - 3 : v; }

template<bool EDGE>
__device__ __forceinline__ void load_row(const float* __restrict__ x,
                                         const float* __restrict__ op,
                                         int fbase, int mrow,
                                         float (&yc)[3][8], float (&oc)[3][8])
{
#pragma unroll
    for (int c = 0; c < 3; ++c) {
        const int fb = fbase + c * CHS;
        const int mc = mod3s(mrow + c);            // fb % 3
        const bool m_is[3] = { mc == 0, mc == 1, mc == 2 };
        int f0 = fb, f1 = fb + 4, f2 = fb + 8;
        if (EDGE) {
            f0 = min(max(f0, 0), NTOT - 4);
            f1 = min(max(f1, 0), NTOT - 4);
            f2 = min(max(f2, 0), NTOT - 4);
        }
        float xw[12], ow[12];
        *(float4*)&xw[0] = *(const float4*)(x + f0);
        *(float4*)&xw[4] = *(const float4*)(x + f1);
        *(float4*)&xw[8] = *(const float4*)(x + f2);
        *(float4*)&ow[0] = *(const float4*)(op + f0);
        *(float4*)&ow[4] = *(const float4*)(op + f1);
        *(float4*)&ow[8] = *(const float4*)(op + f2);
#pragma unroll
        for (int i = 2; i <= 9; ++i) {
            // candidate per j (group alignment): all static x-window indices
            const float c0 = fmaf(xw[i],    0.257f, fmaf(xw[i+1],  0.564f, fmaf(xw[i+2],  0.098f, 16.f/255.f)));
            const float c1 = fmaf(xw[i-1], -0.148f, fmaf(xw[i],   -0.291f, fmaf(xw[i+1],  0.439f, 128.f/255.f)));
            const float c2 = fmaf(xw[i-2],  0.439f, fmaf(xw[i-1], -0.368f, fmaf(xw[i],   -0.071f, 128.f/255.f)));
            const int t0 = (3 - (i % 3)) % 3;      // j==0  <=>  mc == t0
            const int t1 = (4 - (i % 3)) % 3;      // j==1  <=>  mc == t1
            yc[c][i-2] = m_is[t0] ? c0 : (m_is[t1] ? c1 : c2);
            oc[c][i-2] = ow[i];
        }
    }
}

__device__ __forceinline__ void stash(float (&yb)[3][4], float (&ob)[3][4],
                                      const float (&yc)[3][8], const float (&oc)[3][8])
{
#pragma unroll
    for (int c = 0; c < 3; ++c)
#pragma unroll
        for (int p = 0; p < 4; ++p) { yb[c][p] = yc[c][p+2]; ob[c][p] = oc[c][p+2]; }
}

template<bool EDGE>
__device__ __forceinline__ void pairs_dy0(const float (&yc)[3][8], const float (&oc)[3][8],
                                          const bool (&cv)[8], float& acc)
{
#pragma unroll
    for (int dx = 1; dx <= 2; ++dx) {
        const float inv = 2.0f / (float)(NB * HH * (WW - dx));
#pragma unroll
        for (int p = 0; p < 4; ++p) {
            const int k = p + dx + 2, kb = p + 2;
            const float d0 = yc[0][k] - yc[0][kb];
            const float d1 = yc[1][k] - yc[1][kb];
            const float d2 = yc[2][k] - yc[2][kb];
            const float ss = fmaf(d2, d2, fmaf(d1, d1, d0 * d0));
            const float sad = fabsf(oc[0][k] - oc[0][kb]) + fabsf(oc[1][k] - oc[1][kb])
                            + fabsf(oc[2][k] - oc[2][kb]);
            const float sc = (!EDGE || cv[k]) ? inv : 0.f;
            acc = fmaf(sc * exp2f(SC2 * ss), sad, acc);
        }
    }
}

template<int DY, bool EDGE>
__device__ __forceinline__ void pairs_dyn(const float (&yc)[3][8], const float (&oc)[3][8],
                                          const float (&yb)[3][4], const float (&ob)[3][4],
                                          const bool (&cv)[8], float& acc)
{
#pragma unroll
    for (int dx = -2; dx <= 2; ++dx) {
        const int adx = dx < 0 ? -dx : dx;
        const float inv = 2.0f / (float)(NB * (HH - DY) * (WW - adx));
#pragma unroll
        for (int p = 0; p < 4; ++p) {
            const int k = p + dx + 2;              // 0..7
            const float d0 = yc[0][k] - yb[0][p];
            const float d1 = yc[1][k] - yb[1][p];
            const float d2 = yc[2][k] - yb[2][p];
            const float ss = fmaf(d2, d2, fmaf(d1, d1, d0 * d0));
            const float sad = fabsf(oc[0][k] - ob[0][p]) + fabsf(oc[1][k] - ob[1][p])
                            + fabsf(oc[2][k] - ob[2][p]);
            const float sc = (!EDGE || cv[k]) ? inv : 0.f;
            acc = fmaf(sc * exp2f(SC2 * ss), sad, acc);
        }
    }
}

template<bool EDGE>
__device__ __forceinline__ float run_strip(const float* __restrict__ x,
                                           const float* __restrict__ op,
                                           int wq, int rb, int b)
{
    bool cv[8];
#pragma unroll
    for (int k = 0; k < 8; ++k) cv[k] = !EDGE || ((unsigned)(wq - 2 + k) < (unsigned)WW);

    const int fb0 = (b * 3 * HH + rb) * WW + (wq - 4);   // c=0, s=0 window base
    int mrow = (2 * rb + wq + 2) % 3;                    // fb0 % 3 (nonneg form)

    float yp[2][3][4], opv[2][3][4];
    float yc[3][8], oc[3][8];
    float acc = 0.f;

    // rows s = 0..5: owned rows s<4 (dy0 + stash); s=4,5 are halo (neighbor only)
    // s = 0
    load_row<EDGE>(x, op, fb0, mrow, yc, oc);
    pairs_dy0<EDGE>(yc, oc, cv, acc);
    stash(yp[0], opv[0], yc, oc);
    // s = 1
    mrow = mod3s(mrow + 2);
    load_row<EDGE>(x, op, fb0 + WW, mrow, yc, oc);
    pairs_dy0<EDGE>(yc, oc, cv, acc);
    pairs_dyn<1, EDGE>(yc, oc, yp[0], opv[0], cv, acc);
    stash(yp[1], opv[1], yc, oc);
    // s = 2
    mrow = mod3s(mrow + 2);
    load_row<EDGE>(x, op, fb0 + 2 * WW, mrow, yc, oc);
    pairs_dy0<EDGE>(yc, oc, cv, acc);
    pairs_dyn<1, EDGE>(yc, oc, yp[1], opv[1], cv, acc);   // base row 1
    pairs_dyn<2, EDGE>(yc, oc, yp[0], opv[0], cv, acc);   // base row 0
    stash(yp[0], opv[0], yc, oc);
    // s = 3
    mrow = mod3s(mrow + 2);
    load_row<EDGE>(x, op, fb0 + 3 * WW, mrow, yc, oc);
    pairs_dy0<EDGE>(yc, oc, cv, acc);
    pairs_dyn<1, EDGE>(yc, oc, yp[0], opv[0], cv, acc);   // base row 2
    pairs_dyn<2, EDGE>(yc, oc, yp[1], opv[1], cv, acc);   // base row 1
    stash(yp[1], opv[1], yc, oc);
    // s = 4 (halo)
    mrow = mod3s(mrow + 2);
    if (!EDGE || (rb + 4) < HH) {
        load_row<EDGE>(x, op, fb0 + 4 * WW, mrow, yc, oc);
        pairs_dyn<1, EDGE>(yc, oc, yp[1], opv[1], cv, acc);   // base row 3
        pairs_dyn<2, EDGE>(yc, oc, yp[0], opv[0], cv, acc);   // base row 2
    }
    // s = 5 (halo)
    mrow = mod3s(mrow + 2);
    if (!EDGE || (rb + 5) < HH) {
        load_row<EDGE>(x, op, fb0 + 5 * WW, mrow, yc, oc);
        pairs_dyn<2, EDGE>(yc, oc, yp[1], opv[1], cv, acc);   // base row 3
    }
    return acc;
}

__global__ __launch_bounds__(256)
void smooth_loss_kernel(const float* __restrict__ x, const float* __restrict__ op,
                        float* __restrict__ total)
{
    const int tx  = threadIdx.x;                    // 0..31
    const int ty  = threadIdx.y;                    // 0..7
    const int tid = ty * 32 + tx;
    const int bx  = blockIdx.x, by = blockIdx.y, b = blockIdx.z;
    const int wq  = bx * 128 + 4 * tx;              // first owned col
    const int rb  = by * 32 + 4 * ty;               // first owned row

    float acc;
    if ((bx == 1 || bx == 2) && by < 15)            // block-uniform branch
        acc = run_strip<false>(x, op, wq, rb, b);
    else
        acc = run_strip<true>(x, op, wq, rb, b);

    // ---- reduction: wave shuffle -> LDS -> one atomic per block ----
#pragma unroll
    for (int off = 32; off > 0; off >>= 1)
        acc += __shfl_down(acc, off, 64);

    __shared__ float s_part[4];
    if ((tid & 63) == 0) s_part[tid >> 6] = acc;
    __syncthreads();
    if (tid == 0)
        atomicAdd(total, s_part[0] + s_part[1] + s_part[2] + s_part[3]);
}

extern "C" void kernel_launch(void* const* d_in, const int* in_sizes, int n_in,
                              void* d_out, int out_size, void* d_ws, size_t ws_size,
                              hipStream_t stream) {
    const float* x  = (const float*)d_in[0];   // "input"  [16,3,512,512] fp32
    const float* op = (const float*)d_in[1];   // "output" [16,3,512,512] fp32
    float* total = (float*)d_out;              // scalar fp32

    hipMemsetAsync(total, 0, sizeof(float), stream);

    dim3 grid(4, 16, NB);                      // 1024 blocks
    dim3 block(32, 8);                         // 256 threads; strip 4x4 each
    smooth_loss_kernel<<<grid, block, 0, stream>>>(x, op, total);
}

// Round 7
// 65.095 us; speedup vs baseline: 1.5560x; 1.5560x over previous
//
#include <hip/hip_runtime.h>

#define HH 512
#define WW 512
#define NB 16
#define NTOT (NB * 3 * HH * WW)     // 12582912
#define CHS (HH * WW)               // 262144 (channel stride), CHS % 3 == 1

// Each thread owns a 4-wide x 4-tall strip. No LDS (except final reduction).
// Rolling register history of 2 previous rows (own 4 cols); current row holds
// 8 cols (own 4 + dx-halo +/-2). ycc built on the fly from a 12-float x window:
// ycc[f] = x[f-j]*mat[0][j] + x[f-j+1]*mat[1][j] + x[f-j+2]*mat[2][j] + bias[j],
// j = f % 3 (faithful to reference's reshape(-1,3) @ mat over flat NCHW).
// 12 unique offsets, each counted twice in the reference -> factor 2 in inv.
// NOTE: keep the `#pragma unroll 1` rolled loop — full unrolling spills (R6:
// 256 VGPR + 16.8 MB scratch writes, 59.6 -> 101 us).

#define SC2 (-0.0072134752044448f)  // -1/(2*sigma^2) * log2(e), sigma=10

__device__ __forceinline__ int mod3s(int v) { return v >= 3 ? v - 3 : v; }

__device__ __forceinline__ void load_row(const float* __restrict__ x,
                                         const float* __restrict__ op,
                                         int fbase, int mrow,
                                         float (&yc)[3][8], float (&oc)[3][8])
{
#pragma unroll
    for (int c = 0; c < 3; ++c) {
        const int fb = fbase + c * CHS;
        int mc = mod3s(mrow + c);                  // fb % 3
        const bool m_is[3] = { mc == 0, mc == 1, mc == 2 };
        const int f0 = min(max(fb,     0), NTOT - 4);
        const int f1 = min(max(fb + 4, 0), NTOT - 4);
        const int f2 = min(max(fb + 8, 0), NTOT - 4);
        float xw[12], ow[12];
        *(float4*)&xw[0] = *(const float4*)(x + f0);
        *(float4*)&xw[4] = *(const float4*)(x + f1);
        *(float4*)&xw[8] = *(const float4*)(x + f2);
        *(float4*)&ow[0] = *(const float4*)(op + f0);
        *(float4*)&ow[4] = *(const float4*)(op + f1);
        *(float4*)&ow[8] = *(const float4*)(op + f2);
#pragma unroll
        for (int i = 2; i <= 9; ++i) {
            // candidate per j (group alignment): all static x-window indices
            const float c0 = fmaf(xw[i],    0.257f, fmaf(xw[i+1],  0.564f, fmaf(xw[i+2],  0.098f, 16.f/255.f)));
            const float c1 = fmaf(xw[i-1], -0.148f, fmaf(xw[i],   -0.291f, fmaf(xw[i+1],  0.439f, 128.f/255.f)));
            const float c2 = fmaf(xw[i-2],  0.439f, fmaf(xw[i-1], -0.368f, fmaf(xw[i],   -0.071f, 128.f/255.f)));
            const int t0 = (3 - (i % 3)) % 3;      // j==0  <=>  mc == t0
            const int t1 = (4 - (i % 3)) % 3;      // j==1  <=>  mc == t1
            yc[c][i-2] = m_is[t0] ? c0 : (m_is[t1] ? c1 : c2);
            oc[c][i-2] = ow[i];
        }
    }
}

__device__ __forceinline__ void stash(float (&yb)[3][4], float (&ob)[3][4],
                                      const float (&yc)[3][8], const float (&oc)[3][8])
{
#pragma unroll
    for (int c = 0; c < 3; ++c)
#pragma unroll
        for (int p = 0; p < 4; ++p) { yb[c][p] = yc[c][p+2]; ob[c][p] = oc[c][p+2]; }
}

__device__ __forceinline__ void pairs_dy0(const float (&yc)[3][8], const float (&oc)[3][8],
                                          const bool (&cv)[8], float& acc)
{
#pragma unroll
    for (int dx = 1; dx <= 2; ++dx) {
        const float inv = 2.0f / (float)(NB * HH * (WW - dx));
#pragma unroll
        for (int p = 0; p < 4; ++p) {
            const int k = p + dx + 2, kb = p + 2;
            const float d0 = yc[0][k] - yc[0][kb];
            const float d1 = yc[1][k] - yc[1][kb];
            const float d2 = yc[2][k] - yc[2][kb];
            const float ss = fmaf(d2, d2, fmaf(d1, d1, d0 * d0));
            const float sad = fabsf(oc[0][k] - oc[0][kb]) + fabsf(oc[1][k] - oc[1][kb])
                            + fabsf(oc[2][k] - oc[2][kb]);
            const float sc = cv[k] ? inv : 0.f;
            acc = fmaf(sc * exp2f(SC2 * ss), sad, acc);
        }
    }
}

template<int DY>
__device__ __forceinline__ void pairs_dyn(const float (&yc)[3][8], const float (&oc)[3][8],
                                          const float (&yb)[3][4], const float (&ob)[3][4],
                                          const bool (&cv)[8], float& acc)
{
#pragma unroll
    for (int dx = -2; dx <= 2; ++dx) {
        const int adx = dx < 0 ? -dx : dx;
        const float inv = 2.0f / (float)(NB * (HH - DY) * (WW - adx));
#pragma unroll
        for (int p = 0; p < 4; ++p) {
            const int k = p + dx + 2;              // 0..7
            const float d0 = yc[0][k] - yb[0][p];
            const float d1 = yc[1][k] - yb[1][p];
            const float d2 = yc[2][k] - yb[2][p];
            const float ss = fmaf(d2, d2, fmaf(d1, d1, d0 * d0));
            const float sad = fabsf(oc[0][k] - ob[0][p]) + fabsf(oc[1][k] - ob[1][p])
                            + fabsf(oc[2][k] - ob[2][p]);
            const float sc = cv[k] ? inv : 0.f;
            acc = fmaf(sc * exp2f(SC2 * ss), sad, acc);
        }
    }
}

__global__ __launch_bounds__(256)
void smooth_loss_kernel(const float* __restrict__ x, const float* __restrict__ op,
                        float* __restrict__ total)
{
    const int tx  = threadIdx.x;                    // 0..31
    const int ty  = threadIdx.y;                    // 0..7
    const int tid = ty * 32 + tx;
    const int wq  = blockIdx.x * 128 + 4 * tx;      // first owned col
    const int rb  = blockIdx.y * 32 + 4 * ty;       // first owned row (<= 508)
    const int b   = blockIdx.z;

    // col validity of image col wq-2+k, k=0..7
    bool cv[8];
#pragma unroll
    for (int k = 0; k < 8; ++k) cv[k] = ((unsigned)(wq - 2 + k) < (unsigned)WW);

    const int fb0 = (b * 3 * HH + rb) * WW + (wq - 4);   // c=0, s=0 window base
    int mrow = (2 * rb + wq + 2) % 3;                    // fb0 % 3 (nonneg form)

    float yp[2][3][4], opv[2][3][4];
    float yc[3][8], oc[3][8];
    float acc = 0.f;

    // ---- s = 0 ----
    load_row(x, op, fb0, mrow, yc, oc);
    pairs_dy0(yc, oc, cv, acc);
    stash(yp[0], opv[0], yc, oc);
    // ---- s = 1 ----
    mrow = mod3s(mrow + 2);
    load_row(x, op, fb0 + WW, mrow, yc, oc);
    pairs_dy0(yc, oc, cv, acc);
    pairs_dyn<1>(yc, oc, yp[0], opv[0], cv, acc);
    stash(yp[1], opv[1], yc, oc);

#pragma unroll 1
    for (int s = 2; s < 6; s += 2) {
        // ---- row A = s: slot0 holds s-2, slot1 holds s-1 ----
        mrow = mod3s(mrow + 2);
        const bool rokA = (rb + s) < HH;           // neighbor-row validity
        load_row(x, op, fb0 + s * WW, mrow, yc, oc);
        if (s < 4) pairs_dy0(yc, oc, cv, acc);
        if (rokA) {
            pairs_dyn<1>(yc, oc, yp[1], opv[1], cv, acc);   // base row s-1
            pairs_dyn<2>(yc, oc, yp[0], opv[0], cv, acc);   // base row s-2
        }
        if (s < 4) stash(yp[0], opv[0], yc, oc);
        // ---- row B = s+1: slot0 holds s, slot1 holds s-1 ----
        mrow = mod3s(mrow + 2);
        const bool rokB = (rb + s + 1) < HH;
        load_row(x, op, fb0 + (s + 1) * WW, mrow, yc, oc);
        if (s + 1 < 4) pairs_dy0(yc, oc, cv, acc);
        if (rokB) {
            if (s < 4) pairs_dyn<1>(yc, oc, yp[0], opv[0], cv, acc);  // base row s
            pairs_dyn<2>(yc, oc, yp[1], opv[1], cv, acc);             // base row s-1
        }
        if (s + 1 < 4) stash(yp[1], opv[1], yc, oc);
    }

    // ---- reduction: wave shuffle -> LDS -> one atomic per block ----
#pragma unroll
    for (int off = 32; off > 0; off >>= 1)
        acc += __shfl_down(acc, off, 64);

    __shared__ float s_part[4];
    if ((tid & 63) == 0) s_part[tid >> 6] = acc;
    __syncthreads();
    if (tid == 0)
        atomicAdd(total, s_part[0] + s_part[1] + s_part[2] + s_part[3]);
}

extern "C" void kernel_launch(void* const* d_in, const int* in_sizes, int n_in,
                              void* d_out, int out_size, void* d_ws, size_t ws_size,
                              hipStream_t stream) {
    const float* x  = (const float*)d_in[0];   // "input"  [16,3,512,512] fp32
    const float* op = (const float*)d_in[1];   // "output" [16,3,512,512] fp32
    float* total = (float*)d_out;              // scalar fp32

    hipMemsetAsync(total, 0, sizeof(float), stream);

    dim3 grid(4, 16, NB);                      // 1024 blocks
    dim3 block(32, 8);                         // 256 threads; strip 4x4 each
    smooth_loss_kernel<<<grid, block, 0, stream>>>(x, op, total);
}

// Round 8
// 48.414 us; speedup vs baseline: 2.0921x; 1.3445x over previous
//
#include <hip/hip_runtime.h>

#define HH 512
#define WW 512
#define NB 16
#define NTOT (NB * 3 * HH * WW)     // 12582912
#define CHS (HH * WW)               // 262144 (channel stride), CHS % 3 == 1

// 4-wide x 8-tall strips, no LDS (except reduction). Rolling 2-row history.
// ycc[f] = x[f-j]*mat[0][j] + x[f-j+1]*mat[1][j] + x[f-j+2]*mat[2][j] + bias[j],
// j = f % 3 (reference's reshape(-1,3) @ mat over flat NCHW memory).
// 5-tap form: ycc[fb+2+k] = B[j] + sum_s xw[k+s]*C[j][s]  (2 taps are zero),
// with j = (mrow + c + k + 2) % 3, mrow = fb0 % 3. Per row we build the rotated
// coef array Rot[p] = C[(mrow+p)%3] (cndmask), then elements index it STATICALLY
// via p = (c+k+2)%3 -> 5 FMA per element, zero per-element selects.
// 12 unique offsets, each counted twice in the reference -> factor 2 in inv.
// KEEP the rolled `#pragma unroll 1` loop: full unroll spills (R6: 256 VGPR).

#define SC2 (-0.0072134752044448f)  // -1/(2*sigma^2) * log2(e), sigma=10

__device__ __forceinline__ int mod3s(int v) { return v >= 3 ? v - 3 : v; }

// T[j][s]: 5-tap coefficients; Tb[j]: bias
__device__ __constant__ float c_unused;  // keep section non-empty

__device__ __forceinline__ void build_rot(int mrow, float (&Rc)[3][5], float (&Rb)[3])
{
    constexpr float T[3][5] = {
        { 0.f,     0.f,     0.257f, 0.564f, 0.098f },   // j=0
        { 0.f,    -0.148f, -0.291f, 0.439f, 0.f    },   // j=1
        { 0.439f, -0.368f, -0.071f, 0.f,    0.f    } }; // j=2
    constexpr float Tb[3] = { 16.f/255.f, 128.f/255.f, 128.f/255.f };
    const bool is1 = (mrow == 1);
    const bool is2 = (mrow == 2);
#pragma unroll
    for (int p = 0; p < 3; ++p) {
#pragma unroll
        for (int s = 0; s < 5; ++s) {
            const float v0 = T[p][s], v1 = T[(p+1)%3][s], v2 = T[(p+2)%3][s];
            Rc[p][s] = is1 ? v1 : (is2 ? v2 : v0);
        }
        Rb[p] = is1 ? Tb[(p+1)%3] : (is2 ? Tb[(p+2)%3] : Tb[p]);
    }
}

template<bool EDGE>
__device__ __forceinline__ void load_make(const float* __restrict__ x,
                                          const float* __restrict__ op,
                                          int fbase,
                                          const float (&Rc)[3][5], const float (&Rb)[3],
                                          float (&yc)[3][8], float (&oc)[3][8])
{
#pragma unroll
    for (int c = 0; c < 3; ++c) {
        const int fb = fbase + c * CHS;
        int f0 = fb, f1 = fb + 4, f2 = fb + 8;
        if (EDGE) {
            f0 = min(max(f0, 0), NTOT - 4);
            f1 = min(max(f1, 0), NTOT - 4);
            f2 = min(max(f2, 0), NTOT - 4);
        }
        float xw[12], ow[12];
        *(float4*)&xw[0] = *(const float4*)(x + f0);
        *(float4*)&xw[4] = *(const float4*)(x + f1);
        *(float4*)&xw[8] = *(const float4*)(x + f2);
        *(float4*)&ow[0] = *(const float4*)(op + f0);
        *(float4*)&ow[4] = *(const float4*)(op + f1);
        *(float4*)&ow[8] = *(const float4*)(op + f2);
#pragma unroll
        for (int k = 0; k < 8; ++k) {
            const int q = (c + k + 2) % 3;         // static after unroll
            float a = Rb[q];
#pragma unroll
            for (int s = 0; s < 5; ++s)
                a = fmaf(xw[k + s], Rc[q][s], a);
            yc[c][k] = a;
            oc[c][k] = ow[k + 2];
        }
    }
}

__device__ __forceinline__ void stash(float (&yb)[3][4], float (&ob)[3][4],
                                      const float (&yc)[3][8], const float (&oc)[3][8])
{
#pragma unroll
    for (int c = 0; c < 3; ++c)
#pragma unroll
        for (int p = 0; p < 4; ++p) { yb[c][p] = yc[c][p+2]; ob[c][p] = oc[c][p+2]; }
}

template<bool EDGE>
__device__ __forceinline__ void pairs_dy0(const float (&yc)[3][8], const float (&oc)[3][8],
                                          const bool (&cv)[8], float& acc)
{
#pragma unroll
    for (int dx = 1; dx <= 2; ++dx) {
        const float inv = 2.0f / (float)(NB * HH * (WW - dx));
#pragma unroll
        for (int p = 0; p < 4; ++p) {
            const int k = p + dx + 2, kb = p + 2;
            const float d0 = yc[0][k] - yc[0][kb];
            const float d1 = yc[1][k] - yc[1][kb];
            const float d2 = yc[2][k] - yc[2][kb];
            const float ss = fmaf(d2, d2, fmaf(d1, d1, d0 * d0));
            const float sad = fabsf(oc[0][k] - oc[0][kb]) + fabsf(oc[1][k] - oc[1][kb])
                            + fabsf(oc[2][k] - oc[2][kb]);
            const float sc = (!EDGE || cv[k]) ? inv : 0.f;
            acc = fmaf(sc * exp2f(SC2 * ss), sad, acc);
        }
    }
}

template<int DY, bool EDGE>
__device__ __forceinline__ void pairs_dyn(const float (&yc)[3][8], const float (&oc)[3][8],
                                          const float (&yb)[3][4], const float (&ob)[3][4],
                                          const bool (&cv)[8], float& acc)
{
#pragma unroll
    for (int dx = -2; dx <= 2; ++dx) {
        const int adx = dx < 0 ? -dx : dx;
        const float inv = 2.0f / (float)(NB * (HH - DY) * (WW - adx));
#pragma unroll
        for (int p = 0; p < 4; ++p) {
            const int k = p + dx + 2;              // 0..7
            const float d0 = yc[0][k] - yb[0][p];
            const float d1 = yc[1][k] - yb[1][p];
            const float d2 = yc[2][k] - yb[2][p];
            const float ss = fmaf(d2, d2, fmaf(d1, d1, d0 * d0));
            const float sad = fabsf(oc[0][k] - ob[0][p]) + fabsf(oc[1][k] - ob[1][p])
                            + fabsf(oc[2][k] - ob[2][p]);
            const float sc = (!EDGE || cv[k]) ? inv : 0.f;
            acc = fmaf(sc * exp2f(SC2 * ss), sad, acc);
        }
    }
}

template<bool EDGE>
__device__ __forceinline__ float run_strip(const float* __restrict__ x,
                                           const float* __restrict__ op,
                                           int wq, int rb, int b)
{
    bool cv[8];
#pragma unroll
    for (int k = 0; k < 8; ++k) cv[k] = !EDGE || ((unsigned)(wq - 2 + k) < (unsigned)WW);

    const int fb0 = (b * 3 * HH + rb) * WW + (wq - 4);   // c=0, s=0 window base
    int mrow = (2 * rb + wq + 2) % 3;                    // fb0 % 3 (nonneg form)

    float Rc[3][5], Rb[3];
    float yp[2][3][4], opv[2][3][4];
    float yc[3][8], oc[3][8];
    float acc = 0.f;

    // ---- s = 0 ----
    build_rot(mrow, Rc, Rb);
    load_make<EDGE>(x, op, fb0, Rc, Rb, yc, oc);
    pairs_dy0<EDGE>(yc, oc, cv, acc);
    stash(yp[0], opv[0], yc, oc);
    // ---- s = 1 ----
    mrow = mod3s(mrow + 2);
    build_rot(mrow, Rc, Rb);
    load_make<EDGE>(x, op, fb0 + WW, Rc, Rb, yc, oc);
    pairs_dy0<EDGE>(yc, oc, cv, acc);
    pairs_dyn<1, EDGE>(yc, oc, yp[0], opv[0], cv, acc);
    stash(yp[1], opv[1], yc, oc);

#pragma unroll 1
    for (int s = 2; s < 10; s += 2) {
        // ---- row A = s: slot0 holds s-2, slot1 holds s-1 ----
        mrow = mod3s(mrow + 2);
        build_rot(mrow, Rc, Rb);
        const bool rokA = !EDGE || (rb + s) < HH;
        load_make<EDGE>(x, op, fb0 + s * WW, Rc, Rb, yc, oc);
        if (s < 8) pairs_dy0<EDGE>(yc, oc, cv, acc);
        if (rokA) {
            pairs_dyn<1, EDGE>(yc, oc, yp[1], opv[1], cv, acc);   // base row s-1
            pairs_dyn<2, EDGE>(yc, oc, yp[0], opv[0], cv, acc);   // base row s-2
        }
        if (s < 8) stash(yp[0], opv[0], yc, oc);
        // ---- row B = s+1: slot0 holds s, slot1 holds s-1 ----
        mrow = mod3s(mrow + 2);
        build_rot(mrow, Rc, Rb);
        const bool rokB = !EDGE || (rb + s + 1) < HH;
        load_make<EDGE>(x, op, fb0 + (s + 1) * WW, Rc, Rb, yc, oc);
        if (s + 1 < 8) pairs_dy0<EDGE>(yc, oc, cv, acc);
        if (rokB) {
            if (s < 8) pairs_dyn<1, EDGE>(yc, oc, yp[0], opv[0], cv, acc);  // base row s
            pairs_dyn<2, EDGE>(yc, oc, yp[1], opv[1], cv, acc);             // base row s-1
        }
        if (s + 1 < 8) stash(yp[1], opv[1], yc, oc);
    }

    return acc;
}

__global__ __launch_bounds__(256)
void smooth_loss_kernel(const float* __restrict__ x, const float* __restrict__ op,
                        float* __restrict__ total)
{
    const int tx  = threadIdx.x;                    // 0..31
    const int ty  = threadIdx.y;                    // 0..7
    const int tid = ty * 32 + tx;
    const int bx  = blockIdx.x, by = blockIdx.y, b = blockIdx.z;
    const int wq  = bx * 128 + 4 * tx;              // first owned col
    const int rb  = by * 64 + 8 * ty;               // first owned row (<= 504)

    // interior blocks (44%): windows never touch image edges -> no clamps/selects
    float acc;
    if ((bx == 1 || bx == 2) && by < 7)             // block-uniform branch
        acc = run_strip<false>(x, op, wq, rb, b);
    else
        acc = run_strip<true>(x, op, wq, rb, b);

    // ---- reduction: wave shuffle -> LDS -> one atomic per block ----
#pragma unroll
    for (int off = 32; off > 0; off >>= 1)
        acc += __shfl_down(acc, off, 64);

    __shared__ float s_part[4];
    if ((tid & 63) == 0) s_part[tid >> 6] = acc;
    __syncthreads();
    if (tid == 0)
        atomicAdd(total, s_part[0] + s_part[1] + s_part[2] + s_part[3]);
}

extern "C" void kernel_launch(void* const* d_in, const int* in_sizes, int n_in,
                              void* d_out, int out_size, void* d_ws, size_t ws_size,
                              hipStream_t stream) {
    const float* x  = (const float*)d_in[0];   // "input"  [16,3,512,512] fp32
    const float* op = (const float*)d_in[1];   // "output" [16,3,512,512] fp32
    float* total = (float*)d_out;              // scalar fp32

    hipMemsetAsync(total, 0, sizeof(float), stream);

    dim3 grid(4, 8, NB);                       // 512 blocks
    dim3 block(32, 8);                         // 256 threads; strip 4x8 each
    smooth_loss_kernel<<<grid, block, 0, stream>>>(x, op, total);
}